// Round 9
// baseline (364.122 us; speedup 1.0000x reference)
//
#include <hip/hip_runtime.h>
#include <hip/hip_bf16.h>

#define DD 63
#define DD2 (DD * DD)   // 3969
#define NSU 8

typedef __attribute__((ext_vector_type(8))) short short8;   // 8 bf16 in 4 VGPRs
typedef __attribute__((ext_vector_type(4))) float f32x4;

// Device-global scratch (rewritten every call -> deterministic).
__device__ float  g_F[DD2 * DD];     // f[a][b][c] = g_F[(a*63+b)*63+c]
__device__ unsigned short g_Gb[64 * 64]; // bf16 row-major: [m*64+k] = 0.01*G[m][k] + 1.01*delta; row/col 63 = 0

__device__ __forceinline__ unsigned short f2bf(float f) {
    union { float f; unsigned u; } v; v.f = f;
    unsigned r = v.u + 0x7FFFu + ((v.u >> 16) & 1u);
    return (unsigned short)(r >> 16);
}

// ---------------------------------------------------------------------------
// fill one Gell-Mann matrix (re/im parts) into an 8x8 region
// ---------------------------------------------------------------------------
__device__ __forceinline__ void fill_L(int a, float (*re)[NSU], float (*im)[NSU]) {
    if (a < 56) {
        int p = a >> 1;
        int j = 0, rem = p;
        while (rem >= 7 - j) { rem -= 7 - j; ++j; }
        int k = j + 1 + rem;
        if ((a & 1) == 0) { re[j][k] = 1.f; re[k][j] = 1.f; }
        else             { im[j][k] = -1.f; im[k][j] = 1.f; }
    } else {
        int l = a - 55;
        float c = sqrtf(2.f / (float)(l * (l + 1)));
        for (int j = 0; j < l; ++j) re[j][j] = c;
        re[l][l] = -(float)l * c;
    }
}

// ---------------------------------------------------------------------------
// Kernel 1: 63 blocks x 256; block a computes f[a,:,:] (wave w does b=4*rb+w)
// ---------------------------------------------------------------------------
__global__ __launch_bounds__(256) void setup_f_kernel() {
    const int t = threadIdx.x;
    const int a = blockIdx.x;
    __shared__ float Ar[NSU][NSU], Ai[NSU][NSU];
    __shared__ float Br[4][NSU][NSU], Bi[4][NSU][NSU];
    __shared__ float Cr[4][NSU][NSU], Ci[4][NSU][NSU];
    const int w = t >> 6, lane = t & 63;
    const int r = lane >> 3, c = lane & 7;
    if (t < 64) { Ar[r][c] = 0.f; Ai[r][c] = 0.f; }
    __syncthreads();
    if (t == 0) fill_L(a, Ar, Ai);
    __syncthreads();
    for (int rb = 0; rb < 16; ++rb) {
        const int b = rb * 4 + w;
        const bool act = (b < DD);
        if (act) { Br[w][r][c] = 0.f; Bi[w][r][c] = 0.f; }
        __syncthreads();
        if (act && lane == 0) fill_L(b, Br[w], Bi[w]);
        __syncthreads();
        if (act) {
            float pr = 0.f, pi = 0.f, qr = 0.f, qi = 0.f;
            #pragma unroll
            for (int k = 0; k < NSU; ++k) {
                pr += Ar[r][k] * Br[w][k][c] - Ai[r][k] * Bi[w][k][c];
                pi += Ar[r][k] * Bi[w][k][c] + Ai[r][k] * Br[w][k][c];
                qr += Br[w][r][k] * Ar[k][c] - Bi[w][r][k] * Ai[k][c];
                qi += Br[w][r][k] * Ai[k][c] + Bi[w][r][k] * Ar[k][c];
            }
            Cr[w][r][c] = pr - qr;
            Ci[w][r][c] = pi - qi;
        }
        __syncthreads();
        if (act && lane < DD) {
            float im;
            if (lane < 56) {
                int p = lane >> 1;
                int j = 0, rem = p;
                while (rem >= 7 - j) { rem -= 7 - j; ++j; }
                int k = j + 1 + rem;
                if ((lane & 1) == 0) im = Ci[w][j][k] + Ci[w][k][j];
                else                 im = Cr[w][j][k] - Cr[w][k][j];
            } else {
                int l = lane - 55;
                float cd = sqrtf(2.f / (float)(l * (l + 1)));
                float s = 0.f;
                for (int j = 0; j < l; ++j) s += Ci[w][j][j];
                im = cd * s - (float)l * cd * Ci[w][l][l];
            }
            g_F[(a * DD + b) * DD + lane] = 0.25f * im;
        }
        __syncthreads();
    }
}

// ---------------------------------------------------------------------------
// Kernel 2: 63 blocks x 256; block n computes column n of G' (all m).
//   cc = v^T v (redundant per block), B[j,k] = sum_i cc[i,j] f[n,i,k],
//   p(m) = sum f[m]·B, h(m) = sum_k f[k,m,n] w[k],
//   g_Gb[m*64+n] = bf16(0.01*(-4*scale*p + 8*h) + 1.01*delta(m,n)).
// Block 0 zeroes pad row/col 63.
// ---------------------------------------------------------------------------
__global__ __launch_bounds__(256) void buildG_kernel(const float* __restrict__ r_x,
                                                     const float* __restrict__ r_y,
                                                     const float* __restrict__ Np,
                                                     const float* __restrict__ omega) {
    __shared__ float v[DD2];
    __shared__ float cc[DD2];
    __shared__ float sf[DD2];
    __shared__ float Bs[DD2];
    __shared__ float s_scale;
    const int t = threadIdx.x;
    const int n = blockIdx.x;

    for (int idx = t; idx < DD2; idx += 256) {
        sf[idx] = g_F[n * DD2 + idx];
        int i = idx / DD, j = idx - i * DD;
        float val = 0.f;
        if (j > i)       val = r_y[62 * i - (i * (i - 1)) / 2 + (j - i - 1)];
        else if (j == i) val = r_x[63 * i - (i * (i - 1)) / 2];
        v[idx] = val;
    }
    __syncthreads();
    for (int idx = t; idx < DD2; idx += 256) {
        int i = idx / DD, j = idx - i * DD;
        float s = 0.f;
        for (int k = 0; k < DD; ++k) s = fmaf(v[k * DD + i], v[k * DD + j], s);
        cc[idx] = s;
    }
    __syncthreads();
    if (t == 0) {
        float tr = 0.f;
        for (int i = 0; i < DD; ++i) tr += cc[i * DD + i];
        s_scale = Np[0] / tr;
    }
    __syncthreads();
    for (int idx = t; idx < DD2; idx += 256) {
        int j = idx / DD, k = idx - j * DD;
        float s = 0.f;
        for (int i = 0; i < DD; ++i) s = fmaf(cc[i * DD + j], sf[i * DD + k], s);
        Bs[idx] = s;
    }
    __syncthreads();

    const int w = t >> 6, lane = t & 63;
    const float sc = s_scale;
    for (int r = 0; r < 16; ++r) {
        const int m = r * 4 + w;
        if (m >= DD) continue;
        const float* __restrict__ Fm = g_F + m * DD2;
        float p = 0.f;
        for (int idx = lane; idx < DD2; idx += 64) p = fmaf(Fm[idx], Bs[idx], p);
        float h = (lane < DD) ? g_F[lane * DD2 + m * DD + n] * omega[lane] : 0.f;
        #pragma unroll
        for (int off = 32; off > 0; off >>= 1) {
            p += __shfl_down(p, off);
            h += __shfl_down(h, off);
        }
        if (lane == 0)
            g_Gb[m * 64 + n] = f2bf(0.01f * (-4.f * sc * p + 8.f * h)
                                    + ((m == n) ? 1.01f : 0.f));
    }
    if (n == 0 && t < 64) {
        g_Gb[63 * 64 + t] = 0;     // pad row
        g_Gb[t * 64 + 63] = 0;     // pad col
    }
}

// ---------------------------------------------------------------------------
// Kernel 3: out = x_bf16 @ G'^T (G' includes 1.01*I), via MFMA.
// Wave-autonomous, ZERO barriers. Per 16-row tile: coalesced float4 loads ->
// wave-private swizzled LDS slab [16][64] -> 4x ds_read_b128 A-frags ->
// 8 MFMA -> D b32-scatter into slab (2 lanes/bank = free) -> float4 readback
// -> coalesced float4 stores. Next tile's loads issued under compute.
// ---------------------------------------------------------------------------
__global__ __launch_bounds__(256) void apply_kernel(const float* __restrict__ x,
                                                    float* __restrict__ out,
                                                    int ntiles, int nwaves) {
    __shared__ float slab[4][16 * 64];      // 16 KB / block, wave-private slices
    const int t = threadIdx.x;
    const int w = t >> 6, lane = t & 63;
    const int mrow = lane & 15, q = lane >> 4;
    float* __restrict__ S = slab[w];

    // B fragments (loaded once; L2-hot): G'[n=nt*16+mrow][k=kt*32+q*8 ..+7]
    const short8* __restrict__ gG = (const short8*)g_Gb;
    short8 bfrag[2][4];
    #pragma unroll
    for (int kt = 0; kt < 2; ++kt)
        #pragma unroll
        for (int nt = 0; nt < 4; ++nt)
            bfrag[kt][nt] = gG[(nt * 16 + mrow) * 8 + kt * 4 + q];

    // zero the col-63 slot of each row (read by A-frags, paired with G'[.,63]=0)
    if (lane < 16) S[lane * 64 + (((15 ^ lane) << 2) | 3)] = 0.f;

    // tile-invariant per-lane element <-> LDS-offset map (used by stage & flush)
    // element (r,c) lives at S[r*64 + (((c>>2)^r)<<2) + (c&3)]
    int soff[4][4];
    #pragma unroll
    for (int i = 0; i < 4; ++i) {
        const int f = i * 64 + lane;
        #pragma unroll
        for (int j = 0; j < 4; ++j) {
            const int e = 4 * f + j;
            const int r = e / 63, c = e - r * 63;
            soff[i][j] = r * 64 + ((((c >> 2) ^ r) << 2) | (c & 3));
        }
    }
    const bool act3 = (lane < 60);          // last float4 group: f < 252

    int tile = blockIdx.x * 4 + w;
    if (tile >= ntiles) return;

    float4 ld[4];
    {
        const float4* __restrict__ gp = (const float4*)(x + (size_t)tile * (16 * DD));
        ld[0] = gp[lane]; ld[1] = gp[lane + 64]; ld[2] = gp[lane + 128];
        if (act3) ld[3] = gp[lane + 192];
    }

    while (true) {
        // stage regs -> swizzled slab
        #pragma unroll
        for (int i = 0; i < 3; ++i) {
            S[soff[i][0]] = ld[i].x; S[soff[i][1]] = ld[i].y;
            S[soff[i][2]] = ld[i].z; S[soff[i][3]] = ld[i].w;
        }
        if (act3) {
            S[soff[3][0]] = ld[3].x; S[soff[3][1]] = ld[3].y;
            S[soff[3][2]] = ld[3].z; S[soff[3][3]] = ld[3].w;
        }
        const size_t tb = (size_t)tile * (16 * DD);
        const int next = tile + nwaves;

        // A fragments: 4 conflict-free ds_read_b128
        float va[2][8];
        #pragma unroll
        for (int kt = 0; kt < 2; ++kt) {
            const int c0 = 8 * kt + 2 * q;
            *(float4*)&va[kt][0] = *(const float4*)&S[mrow * 64 + (((c0    ) ^ mrow) << 2)];
            *(float4*)&va[kt][4] = *(const float4*)&S[mrow * 64 + (((c0 + 1) ^ mrow) << 2)];
        }

        // prefetch next tile under the compute+flush phases
        if (next < ntiles) {
            const float4* __restrict__ gp = (const float4*)(x + (size_t)next * (16 * DD));
            ld[0] = gp[lane]; ld[1] = gp[lane + 64]; ld[2] = gp[lane + 128];
            if (act3) ld[3] = gp[lane + 192];
        }

        short8 af[2];
        #pragma unroll
        for (int kt = 0; kt < 2; ++kt)
            #pragma unroll
            for (int j = 0; j < 8; ++j) {
                __hip_bfloat16 h = __float2bfloat16(va[kt][j]);
                af[kt][j] = *reinterpret_cast<short*>(&h);
            }

        f32x4 acc[4] = {{0.f,0.f,0.f,0.f},{0.f,0.f,0.f,0.f},
                        {0.f,0.f,0.f,0.f},{0.f,0.f,0.f,0.f}};
        #pragma unroll
        for (int nt = 0; nt < 4; ++nt) {
            acc[nt] = __builtin_amdgcn_mfma_f32_16x16x32_bf16(af[0], bfrag[0][nt], acc[nt], 0, 0, 0);
            acc[nt] = __builtin_amdgcn_mfma_f32_16x16x32_bf16(af[1], bfrag[1][nt], acc[nt], 0, 0, 0);
        }

        // D scatter back into slab (b32, exactly 2 lanes/bank per inst = free)
        #pragma unroll
        for (int nt = 0; nt < 4; ++nt) {
            const int ocol = nt * 16 + mrow;
            if (ocol < DD) {
                #pragma unroll
                for (int r = 0; r < 4; ++r) {
                    const int orow = q * 4 + r;
                    S[orow * 64 + ((((ocol >> 2) ^ orow) << 2) | (ocol & 3))] = acc[nt][r];
                }
            }
        }

        // flush: slab -> float4 -> coalesced global store
        #pragma unroll
        for (int i = 0; i < 3; ++i) {
            float4 o;
            o.x = S[soff[i][0]]; o.y = S[soff[i][1]];
            o.z = S[soff[i][2]]; o.w = S[soff[i][3]];
            ((float4*)(out + tb))[i * 64 + lane] = o;
        }
        if (act3) {
            float4 o;
            o.x = S[soff[3][0]]; o.y = S[soff[3][1]];
            o.z = S[soff[3][2]]; o.w = S[soff[3][3]];
            ((float4*)(out + tb))[192 + lane] = o;
        }

        if (next >= ntiles) break;
        tile = next;
    }
}

// ---------------------------------------------------------------------------
extern "C" void kernel_launch(void* const* d_in, const int* in_sizes, int n_in,
                              void* d_out, int out_size, void* d_ws, size_t ws_size,
                              hipStream_t stream) {
    const float* x     = (const float*)d_in[0];
    const float* r_x   = (const float*)d_in[1];
    const float* r_y   = (const float*)d_in[2];
    const float* Np    = (const float*)d_in[3];
    const float* omega = (const float*)d_in[4];
    float* out = (float*)d_out;

    const int rows = in_sizes[0] / DD;          // 1048576
    const int ntiles = rows / 16;               // 65536
    const int ablocks = 2048;                   // 8192 waves, 8 tiles each
    const int nwaves = ablocks * 4;

    setup_f_kernel<<<DD, 256, 0, stream>>>();
    buildG_kernel<<<DD, 256, 0, stream>>>(r_x, r_y, Np, omega);
    apply_kernel<<<ablocks, 256, 0, stream>>>(x, out, ntiles, nwaves);
}

// Round 10
// 180.007 us; speedup vs baseline: 2.0228x; 2.0228x over previous
//
#include <hip/hip_runtime.h>
#include <hip/hip_bf16.h>

#define DD 63
#define DD2 (DD * DD)   // 3969
#define NSU 8

typedef __attribute__((ext_vector_type(8))) short short8;   // 8 bf16 in 4 VGPRs
typedef __attribute__((ext_vector_type(4))) float f32x4;

// Device-global scratch (rewritten every call -> deterministic).
__device__ float  g_F[DD2 * DD];     // f[a][b][c] = g_F[(a*63+b)*63+c]
__device__ float  g_B[DD * DD2];     // B[n][j*63+k] = sum_i cc[i,j] f[n,i,k]
__device__ float  g_cc[DD2];         // cc = v^T v
__device__ float  g_scale;           // N / tr(cc)
__device__ unsigned short g_Gb[64 * 64]; // bf16 row-major: [m*64+k] = 0.01*G[m][k] + 1.01*delta; row/col 63 = 0

__device__ __forceinline__ unsigned short f2bf(float f) {
    union { float f; unsigned u; } v; v.f = f;
    unsigned r = v.u + 0x7FFFu + ((v.u >> 16) & 1u);
    return (unsigned short)(r >> 16);
}

// ---------------------------------------------------------------------------
// fill one Gell-Mann matrix (re/im parts) into an 8x8 region
// ---------------------------------------------------------------------------
__device__ __forceinline__ void fill_L(int a, float (*re)[NSU], float (*im)[NSU]) {
    if (a < 56) {
        int p = a >> 1;
        int j = 0, rem = p;
        while (rem >= 7 - j) { rem -= 7 - j; ++j; }
        int k = j + 1 + rem;
        if ((a & 1) == 0) { re[j][k] = 1.f; re[k][j] = 1.f; }
        else             { im[j][k] = -1.f; im[k][j] = 1.f; }
    } else {
        int l = a - 55;
        float c = sqrtf(2.f / (float)(l * (l + 1)));
        for (int j = 0; j < l; ++j) re[j][j] = c;
        re[l][l] = -(float)l * c;
    }
}

// ---------------------------------------------------------------------------
// Kernel 1: 64 blocks x 256.
//   blocks 0..62 : structure constants f[a,:,:] (wave w does b = 4*rb + w)
//   block 63     : v, cc = v^T v, scale = N / tr(cc)
// ---------------------------------------------------------------------------
__global__ __launch_bounds__(256) void setup_kernel(const float* __restrict__ r_x,
                                                    const float* __restrict__ r_y,
                                                    const float* __restrict__ Np) {
    const int t = threadIdx.x;
    if (blockIdx.x < DD) {
        const int a = blockIdx.x;
        __shared__ float Ar[NSU][NSU], Ai[NSU][NSU];
        __shared__ float Br[4][NSU][NSU], Bi[4][NSU][NSU];
        __shared__ float Cr[4][NSU][NSU], Ci[4][NSU][NSU];
        const int w = t >> 6, lane = t & 63;
        const int r = lane >> 3, c = lane & 7;
        if (t < 64) { Ar[r][c] = 0.f; Ai[r][c] = 0.f; }
        __syncthreads();
        if (t == 0) fill_L(a, Ar, Ai);
        __syncthreads();
        for (int rb = 0; rb < 16; ++rb) {
            const int b = rb * 4 + w;
            const bool act = (b < DD);
            if (act) { Br[w][r][c] = 0.f; Bi[w][r][c] = 0.f; }
            __syncthreads();
            if (act && lane == 0) fill_L(b, Br[w], Bi[w]);
            __syncthreads();
            if (act) {
                float pr = 0.f, pi = 0.f, qr = 0.f, qi = 0.f;
                #pragma unroll
                for (int k = 0; k < NSU; ++k) {
                    pr += Ar[r][k] * Br[w][k][c] - Ai[r][k] * Bi[w][k][c];
                    pi += Ar[r][k] * Bi[w][k][c] + Ai[r][k] * Br[w][k][c];
                    qr += Br[w][r][k] * Ar[k][c] - Bi[w][r][k] * Ai[k][c];
                    qi += Br[w][r][k] * Ai[k][c] + Bi[w][r][k] * Ar[k][c];
                }
                Cr[w][r][c] = pr - qr;
                Ci[w][r][c] = pi - qi;
            }
            __syncthreads();
            if (act && lane < DD) {
                float im;
                if (lane < 56) {
                    int p = lane >> 1;
                    int j = 0, rem = p;
                    while (rem >= 7 - j) { rem -= 7 - j; ++j; }
                    int k = j + 1 + rem;
                    if ((lane & 1) == 0) im = Ci[w][j][k] + Ci[w][k][j];
                    else                 im = Cr[w][j][k] - Cr[w][k][j];
                } else {
                    int l = lane - 55;
                    float cd = sqrtf(2.f / (float)(l * (l + 1)));
                    float s = 0.f;
                    for (int j = 0; j < l; ++j) s += Ci[w][j][j];
                    im = cd * s - (float)l * cd * Ci[w][l][l];
                }
                g_F[(a * DD + b) * DD + lane] = 0.25f * im;
            }
            __syncthreads();
        }
    } else {
        __shared__ float v[DD2];
        __shared__ float ccs[DD2];
        for (int idx = t; idx < DD2; idx += 256) {
            int i = idx / DD, j = idx % DD;
            float val = 0.f;
            if (j > i)       val = r_y[62 * i - (i * (i - 1)) / 2 + (j - i - 1)];
            else if (j == i) val = r_x[63 * i - (i * (i - 1)) / 2];
            v[idx] = val;
        }
        __syncthreads();
        for (int idx = t; idx < DD2; idx += 256) {
            int i = idx / DD, j = idx % DD;
            float s = 0.f;
            for (int k = 0; k < DD; ++k) s = fmaf(v[k * DD + i], v[k * DD + j], s);
            ccs[idx] = s;
            g_cc[idx] = s;
        }
        __syncthreads();
        if (t == 0) {
            float tr = 0.f;
            for (int i = 0; i < DD; ++i) tr += ccs[i * DD + i];
            g_scale = Np[0] / tr;
        }
    }
}

// ---------------------------------------------------------------------------
// Kernel 2: 63 blocks x 256; block n: B[n,j,k] = sum_i cc[i,j] * f[n,i,k].
// ---------------------------------------------------------------------------
__global__ __launch_bounds__(256) void buildB_kernel() {
    __shared__ float scc[DD2];
    __shared__ float sf[DD2];
    const int t = threadIdx.x;
    const int n = blockIdx.x;
    for (int idx = t; idx < DD2; idx += 256) {
        scc[idx] = g_cc[idx];
        sf[idx]  = g_F[n * DD2 + idx];
    }
    __syncthreads();
    for (int idx = t; idx < DD2; idx += 256) {
        const int j = idx / DD, k = idx % DD;
        float s = 0.f;
        for (int i = 0; i < DD; ++i) s = fmaf(scc[i * DD + j], sf[i * DD + k], s);
        g_B[n * DD2 + idx] = s;
    }
}

// ---------------------------------------------------------------------------
// Kernel 3: 64*64 blocks x 64; block (m,n):
//   G'[m][n] = 0.01*(-4*scale*sum f[m]B[n] + 8*sum_k f[k,m,n] w[k]) + 1.01*d(m,n)
//   -> g_Gb[m*64+n] (bf16);  pads (m==63 or n==63) = 0.
// ---------------------------------------------------------------------------
__global__ __launch_bounds__(64) void buildKt_kernel(const float* __restrict__ omega) {
    const int m = blockIdx.x >> 6;          // out-row 0..63
    const int n = blockIdx.x & 63;          // in-col (k) 0..63
    const int lane = threadIdx.x;
    if (m >= DD || n >= DD) {
        if (lane == 0) g_Gb[m * 64 + n] = 0;
        return;
    }
    const float* __restrict__ Fm = g_F + m * DD2;
    const float* __restrict__ Bn = g_B + n * DD2;
    float p = 0.f;
    for (int idx = lane; idx < DD2; idx += 64) p = fmaf(Fm[idx], Bn[idx], p);
    float h = (lane < DD) ? g_F[lane * DD2 + m * DD + n] * omega[lane] : 0.f;
    #pragma unroll
    for (int off = 32; off > 0; off >>= 1) {
        p += __shfl_down(p, off);
        h += __shfl_down(h, off);
    }
    if (lane == 0)
        g_Gb[m * 64 + n] = f2bf(0.01f * (-4.f * g_scale * p + 8.f * h)
                                + ((m == n) ? 1.01f : 0.f));
}

// ---------------------------------------------------------------------------
// Kernel 4: out = x_bf16 @ G'^T (G' includes 1.01*I), via MFMA.
// Wave-autonomous, ZERO barriers. Per 16-row tile: coalesced float4 loads ->
// wave-private swizzled LDS slab [16][64] -> 4x ds_read_b128 A-frags ->
// 8 MFMA -> D b32-scatter into slab (2 lanes/bank = free) -> float4 readback
// -> coalesced float4 stores. Next tile's loads issued under compute.
// ---------------------------------------------------------------------------
__global__ __launch_bounds__(256) void apply_kernel(const float* __restrict__ x,
                                                    float* __restrict__ out,
                                                    int ntiles, int nwaves) {
    __shared__ float slab[4][16 * 64];      // 16 KB / block, wave-private slices
    const int t = threadIdx.x;
    const int w = t >> 6, lane = t & 63;
    const int mrow = lane & 15, q = lane >> 4;
    float* __restrict__ S = slab[w];

    // B fragments (loaded once; L2-hot): G'[n=nt*16+mrow][k=kt*32+q*8 ..+7]
    const short8* __restrict__ gG = (const short8*)g_Gb;
    short8 bfrag[2][4];
    #pragma unroll
    for (int kt = 0; kt < 2; ++kt)
        #pragma unroll
        for (int nt = 0; nt < 4; ++nt)
            bfrag[kt][nt] = gG[(nt * 16 + mrow) * 8 + kt * 4 + q];

    // zero the col-63 slot of each row (read by A-frags, paired with G'[.,63]=0)
    if (lane < 16) S[lane * 64 + (((15 ^ lane) << 2) | 3)] = 0.f;

    // tile-invariant per-lane element <-> LDS-offset map (used by stage & flush)
    // element (r,c) lives at S[r*64 + (((c>>2)^r)<<2) + (c&3)]
    int soff[4][4];
    #pragma unroll
    for (int i = 0; i < 4; ++i) {
        const int f = i * 64 + lane;
        #pragma unroll
        for (int j = 0; j < 4; ++j) {
            const int e = 4 * f + j;
            const int r = e / 63, c = e - r * 63;
            soff[i][j] = r * 64 + ((((c >> 2) ^ r) << 2) | (c & 3));
        }
    }
    const bool act3 = (lane < 60);          // last float4 group: f < 252

    int tile = blockIdx.x * 4 + w;
    if (tile >= ntiles) return;

    float4 ld[4];
    {
        const float4* __restrict__ gp = (const float4*)(x + (size_t)tile * (16 * DD));
        ld[0] = gp[lane]; ld[1] = gp[lane + 64]; ld[2] = gp[lane + 128];
        if (act3) ld[3] = gp[lane + 192];
    }

    while (true) {
        // stage regs -> swizzled slab
        #pragma unroll
        for (int i = 0; i < 3; ++i) {
            S[soff[i][0]] = ld[i].x; S[soff[i][1]] = ld[i].y;
            S[soff[i][2]] = ld[i].z; S[soff[i][3]] = ld[i].w;
        }
        if (act3) {
            S[soff[3][0]] = ld[3].x; S[soff[3][1]] = ld[3].y;
            S[soff[3][2]] = ld[3].z; S[soff[3][3]] = ld[3].w;
        }
        const size_t tb = (size_t)tile * (16 * DD);
        const int next = tile + nwaves;

        // A fragments: 4 conflict-free ds_read_b128
        float va[2][8];
        #pragma unroll
        for (int kt = 0; kt < 2; ++kt) {
            const int c0 = 8 * kt + 2 * q;
            *(float4*)&va[kt][0] = *(const float4*)&S[mrow * 64 + (((c0    ) ^ mrow) << 2)];
            *(float4*)&va[kt][4] = *(const float4*)&S[mrow * 64 + (((c0 + 1) ^ mrow) << 2)];
        }

        // prefetch next tile under the compute+flush phases
        if (next < ntiles) {
            const float4* __restrict__ gp = (const float4*)(x + (size_t)next * (16 * DD));
            ld[0] = gp[lane]; ld[1] = gp[lane + 64]; ld[2] = gp[lane + 128];
            if (act3) ld[3] = gp[lane + 192];
        }

        short8 af[2];
        #pragma unroll
        for (int kt = 0; kt < 2; ++kt)
            #pragma unroll
            for (int j = 0; j < 8; ++j) {
                __hip_bfloat16 h = __float2bfloat16(va[kt][j]);
                af[kt][j] = *reinterpret_cast<short*>(&h);
            }

        f32x4 acc[4] = {{0.f,0.f,0.f,0.f},{0.f,0.f,0.f,0.f},
                        {0.f,0.f,0.f,0.f},{0.f,0.f,0.f,0.f}};
        #pragma unroll
        for (int nt = 0; nt < 4; ++nt) {
            acc[nt] = __builtin_amdgcn_mfma_f32_16x16x32_bf16(af[0], bfrag[0][nt], acc[nt], 0, 0, 0);
            acc[nt] = __builtin_amdgcn_mfma_f32_16x16x32_bf16(af[1], bfrag[1][nt], acc[nt], 0, 0, 0);
        }

        // D scatter back into slab (b32, exactly 2 lanes/bank per inst = free)
        #pragma unroll
        for (int nt = 0; nt < 4; ++nt) {
            const int ocol = nt * 16 + mrow;
            if (ocol < DD) {
                #pragma unroll
                for (int r = 0; r < 4; ++r) {
                    const int orow = q * 4 + r;
                    S[orow * 64 + ((((ocol >> 2) ^ orow) << 2) | (ocol & 3))] = acc[nt][r];
                }
            }
        }

        // flush: slab -> float4 -> coalesced global store
        #pragma unroll
        for (int i = 0; i < 3; ++i) {
            float4 o;
            o.x = S[soff[i][0]]; o.y = S[soff[i][1]];
            o.z = S[soff[i][2]]; o.w = S[soff[i][3]];
            ((float4*)(out + tb))[i * 64 + lane] = o;
        }
        if (act3) {
            float4 o;
            o.x = S[soff[3][0]]; o.y = S[soff[3][1]];
            o.z = S[soff[3][2]]; o.w = S[soff[3][3]];
            ((float4*)(out + tb))[192 + lane] = o;
        }

        if (next >= ntiles) break;
        tile = next;
    }
}

// ---------------------------------------------------------------------------
extern "C" void kernel_launch(void* const* d_in, const int* in_sizes, int n_in,
                              void* d_out, int out_size, void* d_ws, size_t ws_size,
                              hipStream_t stream) {
    const float* x     = (const float*)d_in[0];
    const float* r_x   = (const float*)d_in[1];
    const float* r_y   = (const float*)d_in[2];
    const float* Np    = (const float*)d_in[3];
    const float* omega = (const float*)d_in[4];
    float* out = (float*)d_out;

    const int rows = in_sizes[0] / DD;          // 1048576
    const int ntiles = rows / 16;               // 65536
    const int ablocks = 2048;                   // 8192 waves, 8 tiles each
    const int nwaves = ablocks * 4;

    setup_kernel<<<DD + 1, 256, 0, stream>>>(r_x, r_y, Np);
    buildB_kernel<<<DD, 256, 0, stream>>>();
    buildKt_kernel<<<64 * 64, 64, 0, stream>>>(omega);
    apply_kernel<<<ablocks, 256, 0, stream>>>(x, out, ntiles, nwaves);
}